// Round 8
// baseline (798.028 us; speedup 1.0000x reference)
//
#include <hip/hip_runtime.h>
#include <cmath>

#define BB 64
#define KK 100
#define QQ 100
#define CC 82
#define AA 118
#define KP1 101
#define AM1 117
#define ROWF (KK * KP1)          // 10100 floats per (b,a) row
#define PB 64                    // prep blocks (first in grid)
#define ZB 2496                  // zero blocks; 2496*30300 floats = whole pair
#define ZPB 39                   // zero blocks per batch (117 rows / 3)
#define ZCHUNK4 7575             // float4 per zero block = 3 rows exactly

typedef float vf4 __attribute__((ext_vector_type(4)));

// Scatter-fixup for one batch: n_matched * 117 adds (expected ~140).
__device__ __forceinline__ void do_fixup(
    int b, int tid,
    const float* __restrict__ actions,
    const int* wsf, const float* wsc, const int* wsl, const int* wsn,
    float* __restrict__ out_pair)
{
    int n = wsn[b];
    int total = n * AM1;
    for (int t = tid; t < total; t += 512) {
        int j = t / AM1;
        int a = t - j * AM1;
        int q = wsl[b * QQ + j];
        float c = wsc[b * QQ + q];
        int f = wsf[b * QQ + q];
        float x = actions[((size_t)b * QQ + q) * AA + a];
        atomicAdd(out_pair + ((size_t)(b * AM1 + a)) * ROWF + f,
                  c / (1.f + expf(-x)));
    }
}

// Single kernel. Blocks [0,PB): per-batch prep (scores/labels/boxes +
// per-query f/coef + compacted matched list). Blocks [PB,PB+ZB): contiguous
// float4 zero stream; zero block z covers exactly 3 rows of batch z/39.
// Each batch has 40 participants (39 zero + 1 prep); the 40th to finish
// (tracked by a device-scope counter — no dispatch-order assumption) runs
// that batch's fixup immediately, overlapping other batches' streaming.
__global__ __launch_bounds__(512) void fused_all(
    const float* __restrict__ logits,   // B,K,C
    const float* __restrict__ boxes_in, // B,K,4
    const float* __restrict__ actions,  // B,Q,A
    const float* __restrict__ hidx,     // B,Q,K
    const float* __restrict__ oidx,     // B,Q,K
    const int*   __restrict__ tsizes,   // B,2
    float* __restrict__ out_scores,     // B,K
    float* __restrict__ out_labels,     // B,K
    float* __restrict__ out_boxes,      // B,K,4
    float* __restrict__ out_pair,       // B,117,100,101
    int*   __restrict__ wsf,            // B,Q  flat segment id
    float* __restrict__ wsc,            // B,Q  coefficient (0 if masked out)
    int*   __restrict__ wsl,            // B,Q  compacted matched-q list
    int*   __restrict__ wsn,            // B    matched count
    int*   __restrict__ cnt)            // B    done counters (memset to 0)
{
    int blk = blockIdx.x;
    int tid = threadIdx.x;

    __shared__ int   sh_h[QQ], sh_o[QQ];
    __shared__ float sh_ms[QQ], sh_labf[KK];
    __shared__ int   sh_spos[KK];
    __shared__ float sh_c[QQ];
    __shared__ int   sh_wcnt[2];
    __shared__ int   sh_last;

    if (blk >= PB) {
        int z = blk - PB;
        int b = z / ZPB;
        vf4* dst = ((vf4*)out_pair) + (size_t)z * ZCHUNK4;
        const vf4 zero = {0.f, 0.f, 0.f, 0.f};
        for (int i = tid; i < ZCHUNK4; i += 512)
            dst[i] = zero;
        __threadfence();
        __syncthreads();
        if (tid == 0) sh_last = (atomicAdd(&cnt[b], 1) == ZPB);
        __syncthreads();
        if (sh_last) {
            __threadfence();
            do_fixup(b, tid, actions, wsf, wsc, wsl, wsn, out_pair);
        }
        return;
    }

    int b = blk;

    // ---- phase A: wave-partitioned per-k / per-q tasks ----
    if (tid < KK) {
        // softmax-lite: label (argmax over first 81), score; + boxes
        const float2* l2 = (const float2*)(logits + ((size_t)b * KK + tid) * CC);
        float m = -INFINITY, best = -INFINITY; int bi = 0;
        #pragma unroll
        for (int i = 0; i < CC / 2; ++i) {
            float2 p = l2[i];
            m = fmaxf(m, fmaxf(p.x, p.y));
            if (p.x > best) { best = p.x; bi = 2 * i; }
            if (2 * i + 1 < CC - 1 && p.y > best) { best = p.y; bi = 2 * i + 1; }
        }
        float denom = 0.f;
        #pragma unroll
        for (int i = 0; i < CC / 2; ++i) {
            float2 p = l2[i];
            denom += expf(p.x - m) + expf(p.y - m);
        }
        float score = expf(best - m) / denom;
        sh_labf[tid] = (float)bi;
        sh_spos[tid] = (score > 0.0f) ? 1 : 0;
        out_scores[b * KK + tid] = score;
        out_labels[b * KK + tid] = (float)bi;

        const float4 bx = *(const float4*)(boxes_in + ((size_t)b * KK + tid) * 4);
        float ihh = (float)tsizes[b * 2 + 0];
        float iww = (float)tsizes[b * 2 + 1];
        float4 ob;
        ob.x = (bx.x - 0.5f * bx.z) * iww;
        ob.y = (bx.y - 0.5f * bx.w) * ihh;
        ob.z = (bx.x + 0.5f * bx.z) * iww;
        ob.w = (bx.y + 0.5f * bx.w) * ihh;
        *(float4*)(out_boxes + ((size_t)b * KK + tid) * 4) = ob;
    } else if (tid >= 128 && tid < 128 + QQ) {
        int q = tid - 128;  // argmax hidx (first occurrence, strict >)
        const float4* rp = (const float4*)(hidx + ((size_t)b * QQ + q) * KK);
        float best = -INFINITY; int bi = 0;
        #pragma unroll
        for (int i = 0; i < KK / 4; ++i) {
            float4 r = rp[i];
            if (r.x > best) { best = r.x; bi = 4 * i; }
            if (r.y > best) { best = r.y; bi = 4 * i + 1; }
            if (r.z > best) { best = r.z; bi = 4 * i + 2; }
            if (r.w > best) { best = r.w; bi = 4 * i + 3; }
        }
        sh_h[q] = bi;
    } else if (tid >= 256 && tid < 256 + QQ) {
        int q = tid - 256;  // argmax oidx
        const float4* rp = (const float4*)(oidx + ((size_t)b * QQ + q) * KK);
        float best = -INFINITY; int bi = 0;
        #pragma unroll
        for (int i = 0; i < KK / 4; ++i) {
            float4 r = rp[i];
            if (r.x > best) { best = r.x; bi = 4 * i; }
            if (r.y > best) { best = r.y; bi = 4 * i + 1; }
            if (r.z > best) { best = r.z; bi = 4 * i + 2; }
            if (r.w > best) { best = r.w; bi = 4 * i + 3; }
        }
        sh_o[q] = bi;
    } else if (tid >= 384 && tid < 384 + QQ) {
        int q = tid - 384;  // ms = 1 - sigmoid(last action)
        float x = actions[((size_t)b * QQ + q) * AA + (AA - 1)];
        sh_ms[q] = 1.f - 1.f / (1.f + expf(-x));
    }
    __syncthreads();

    // ---- phase B: winner-per-segment + masked coefficient ----
    if (tid < QQ) {
        int hh = sh_h[tid], oo = sh_o[tid];
        int f = hh * KP1 + oo;
        float myms = sh_ms[tid];
        bool winf = true;
        for (int q = 0; q < QQ; ++q) {
            if (sh_h[q] * KP1 + sh_o[q] == f) {
                float m2 = sh_ms[q];
                if (m2 > myms || (m2 == myms && q < tid)) { winf = false; break; }
            }
        }
        float hm = (sh_labf[hh] == 1.0f && sh_spos[hh]) ? 1.f : 0.f;
        float om = sh_spos[oo] ? 1.f : 0.f;
        float c = myms * (winf ? 2.f : 1.f) * hm * om;
        sh_c[tid] = c;
        wsf[b * QQ + tid] = f;
        wsc[b * QQ + tid] = c;
    }
    __syncthreads();

    // ---- phase C: ballot-compact matched queries (c != 0) ----
    if (tid < 128) {
        bool flag = (tid < QQ) && (sh_c[tid] != 0.f);
        unsigned long long bal = __ballot(flag);
        if ((tid & 63) == 0) sh_wcnt[tid >> 6] = __popcll(bal);
    }
    __syncthreads();
    if (tid < 128) {
        bool flag = (tid < QQ) && (sh_c[tid] != 0.f);
        unsigned long long bal = __ballot(flag);
        int base = (tid >> 6) ? sh_wcnt[0] : 0;
        if (flag) {
            int pos = base + __popcll(bal & ((1ull << (tid & 63)) - 1ull));
            wsl[b * QQ + pos] = tid;
        }
        if (tid == 0) wsn[b] = sh_wcnt[0] + sh_wcnt[1];
    }

    // ---- participate in batch-done counter; maybe run fixup ----
    __threadfence();
    __syncthreads();
    if (tid == 0) sh_last = (atomicAdd(&cnt[b], 1) == ZPB);
    __syncthreads();
    if (sh_last) {
        __threadfence();
        do_fixup(b, tid, actions, wsf, wsc, wsl, wsn, out_pair);
    }
}

extern "C" void kernel_launch(void* const* d_in, const int* in_sizes, int n_in,
                              void* d_out, int out_size, void* d_ws, size_t ws_size,
                              hipStream_t stream) {
    const float* pred_logits  = (const float*)d_in[0];
    const float* pred_boxes   = (const float*)d_in[1];
    const float* pred_actions = (const float*)d_in[2];
    const float* pred_hidx    = (const float*)d_in[3];
    const float* pred_oidx    = (const float*)d_in[4];
    const int*   target_sizes = (const int*)d_in[5];

    float* out = (float*)d_out;
    float* out_scores = out;                // B*K
    float* out_labels = out + BB * KK;      // B*K
    float* out_boxes  = out + 2 * BB * KK;  // B*K*4
    float* out_pair   = out + 6 * BB * KK;  // B*117*100*101

    int*   wsf = (int*)d_ws;                 // B*Q
    float* wsc = (float*)(wsf + BB * QQ);    // B*Q
    int*   wsl = (int*)(wsc + BB * QQ);      // B*Q
    int*   wsn = wsl + BB * QQ;              // B
    int*   cnt = wsn + BB;                   // B done counters

    hipMemsetAsync(cnt, 0, BB * sizeof(int), stream);

    fused_all<<<PB + ZB, 512, 0, stream>>>(
        pred_logits, pred_boxes, pred_actions, pred_hidx, pred_oidx,
        target_sizes, out_scores, out_labels, out_boxes, out_pair,
        wsf, wsc, wsl, wsn, cnt);
}

// Round 9
// 109.645 us; speedup vs baseline: 7.2783x; 7.2783x over previous
//
#include <hip/hip_runtime.h>
#include <cmath>

#define BB 64
#define KK 100
#define QQ 100
#define CC 82
#define AA 118
#define KP1 101
#define AM1 117
#define ROWF (KK * KP1)      // 10100 floats per (b,a) row
#define ZPB 39               // blocks per batch; each covers 3 a-rows
#define NBLK (BB * ZPB)      // 2496 blocks
#define CH4 7575             // float4 per block (3 rows = 30300 floats)

typedef float vf4 __attribute__((ext_vector_type(4)));

// Single kernel, no atomics, no fences, no cross-block communication.
// Block z covers rows (b, r0..r0+2) of pair_score, b = z/39, r0 = 3*(z%39).
// Each block redundantly computes its batch's matched-query list (reads are
// L2-resident across the 39 blocks per batch), streams zeros for its 3 rows,
// then overwrites its own <=3*n matched cells after a block barrier.
__global__ __launch_bounds__(512) void fused_one(
    const float* __restrict__ logits,   // B,K,C
    const float* __restrict__ boxes_in, // B,K,4
    const float* __restrict__ actions,  // B,Q,A
    const float* __restrict__ hidx,     // B,Q,K
    const float* __restrict__ oidx,     // B,Q,K
    const int*   __restrict__ tsizes,   // B,2
    float* __restrict__ out_scores,     // B,K
    float* __restrict__ out_labels,     // B,K
    float* __restrict__ out_boxes,      // B,K,4
    float* __restrict__ out_pair)       // B,117,100,101
{
    int z = blockIdx.x;
    int b = z / ZPB;
    int r0 = (z - b * ZPB) * 3;   // first a-row of this block
    int tid = threadIdx.x;

    __shared__ unsigned char sh_h1[KK];   // label==1 && score>0
    __shared__ unsigned char sh_sp[KK];   // score>0
    __shared__ int   sh_h[QQ], sh_o[QQ];
    __shared__ float sh_ms[QQ];
    __shared__ float sh_c[QQ];
    __shared__ int   sh_wcnt[2];
    __shared__ int   cp_f[QQ];
    __shared__ int   cp_q[QQ];
    __shared__ float cp_c[QQ];
    __shared__ int   sh_n;

    vf4* dst = ((vf4*)out_pair) + (size_t)z * CH4;
    const vf4 zero = {0.f, 0.f, 0.f, 0.f};

    // ---- phase A: prep tasks on waves 0-5; waves 6-7 start the zero stream
    if (tid < 128) {
        if (tid < KK) {
            // logits row k=tid: label (argmax over first 81), score
            const float2* l2 = (const float2*)(logits + ((size_t)b * KK + tid) * CC);
            float m = -INFINITY, best = -INFINITY; int bi = 0;
            #pragma unroll
            for (int i = 0; i < CC / 2; ++i) {
                float2 p = l2[i];
                m = fmaxf(m, fmaxf(p.x, p.y));
                if (p.x > best) { best = p.x; bi = 2 * i; }
                if (2 * i + 1 < CC - 1 && p.y > best) { best = p.y; bi = 2 * i + 1; }
            }
            float denom = 0.f;
            #pragma unroll
            for (int i = 0; i < CC / 2; ++i) {
                float2 p = l2[i];
                denom += expf(p.x - m) + expf(p.y - m);
            }
            float score = expf(best - m) / denom;
            sh_h1[tid] = (unsigned char)((bi == 1 && score > 0.f) ? 1 : 0);
            sh_sp[tid] = (unsigned char)((score > 0.f) ? 1 : 0);
            if (r0 == 0) {  // one block per batch writes the small outputs
                out_scores[b * KK + tid] = score;
                out_labels[b * KK + tid] = (float)bi;
                const float4 bx = *(const float4*)(boxes_in + ((size_t)b * KK + tid) * 4);
                float ihh = (float)tsizes[b * 2 + 0];
                float iww = (float)tsizes[b * 2 + 1];
                float4 ob;
                ob.x = (bx.x - 0.5f * bx.z) * iww;
                ob.y = (bx.y - 0.5f * bx.w) * ihh;
                ob.z = (bx.x + 0.5f * bx.z) * iww;
                ob.w = (bx.y + 0.5f * bx.w) * ihh;
                *(float4*)(out_boxes + ((size_t)b * KK + tid) * 4) = ob;
            }
        }
    } else if (tid < 256) {
        int q = tid - 128;   // argmax hidx + ms
        if (q < QQ) {
            const float4* rp = (const float4*)(hidx + ((size_t)b * QQ + q) * KK);
            float best = -INFINITY; int bi = 0;
            #pragma unroll
            for (int i = 0; i < KK / 4; ++i) {
                float4 r = rp[i];
                if (r.x > best) { best = r.x; bi = 4 * i; }
                if (r.y > best) { best = r.y; bi = 4 * i + 1; }
                if (r.z > best) { best = r.z; bi = 4 * i + 2; }
                if (r.w > best) { best = r.w; bi = 4 * i + 3; }
            }
            sh_h[q] = bi;
            float x = actions[((size_t)b * QQ + q) * AA + (AA - 1)];
            sh_ms[q] = 1.f - 1.f / (1.f + expf(-x));
        }
    } else if (tid < 384) {
        int q = tid - 256;   // argmax oidx
        if (q < QQ) {
            const float4* rp = (const float4*)(oidx + ((size_t)b * QQ + q) * KK);
            float best = -INFINITY; int bi = 0;
            #pragma unroll
            for (int i = 0; i < KK / 4; ++i) {
                float4 r = rp[i];
                if (r.x > best) { best = r.x; bi = 4 * i; }
                if (r.y > best) { best = r.y; bi = 4 * i + 1; }
                if (r.z > best) { best = r.z; bi = 4 * i + 2; }
                if (r.w > best) { best = r.w; bi = 4 * i + 3; }
            }
            sh_o[q] = bi;
        }
    } else {
        // waves 6-7: zero prefix [0, 2560)
        int t = tid - 384;
        #pragma unroll
        for (int k = 0; k < 20; ++k) dst[t + 128 * k] = zero;
    }
    __syncthreads();

    // ---- phase B1: winner+coef on threads 0-99; others zero [2560, 4608)
    if (tid < 128) {
        if (tid < QQ) {
            int hh = sh_h[tid], oo = sh_o[tid];
            int f = hh * KP1 + oo;
            float myms = sh_ms[tid];
            bool winf = true;
            for (int q = 0; q < QQ; ++q) {
                if (sh_h[q] * KP1 + sh_o[q] == f) {
                    float m2 = sh_ms[q];
                    if (m2 > myms || (m2 == myms && q < tid)) { winf = false; break; }
                }
            }
            float c = myms * (winf ? 2.f : 1.f);
            if (!sh_h1[hh] || !sh_sp[oo]) c = 0.f;
            sh_c[tid] = c;
        }
    } else {
        int t = tid - 128;
        #pragma unroll
        for (int k = 0; k < 6; ++k) {
            int i = 2560 + t + 384 * k;
            if (i < 4608) dst[i] = zero;
        }
    }
    __syncthreads();

    // ---- phase B2: ballot counts; others zero [4608, 6144)
    if (tid < 128) {
        bool flag = (tid < QQ) && (sh_c[tid] != 0.f);
        unsigned long long bal = __ballot(flag);
        if ((tid & 63) == 0) sh_wcnt[tid >> 6] = __popcll(bal);
    } else {
        int t = tid - 128;
        #pragma unroll
        for (int k = 0; k < 4; ++k) dst[4608 + t + 384 * k] = zero;
    }
    __syncthreads();

    // ---- phase B3: compacted write; others zero [6144, 7575)
    if (tid < 128) {
        bool flag = (tid < QQ) && (sh_c[tid] != 0.f);
        unsigned long long bal = __ballot(flag);
        int base = (tid >> 6) ? sh_wcnt[0] : 0;
        if (flag) {
            int pos = base + __popcll(bal & ((1ull << (tid & 63)) - 1ull));
            cp_f[pos] = sh_h[tid] * KP1 + sh_o[tid];
            cp_q[pos] = tid;
            cp_c[pos] = sh_c[tid];
        }
        if (tid == 0) sh_n = sh_wcnt[0] + sh_wcnt[1];
    } else {
        int t = tid - 128;
        #pragma unroll
        for (int k = 0; k < 4; ++k) {
            int i = 6144 + t + 384 * k;
            if (i < CH4) dst[i] = zero;
        }
    }
    __syncthreads();

    // ---- phase D: overwrite matched cells in this block's 3 rows ----
    // Barrier above drained all zero stores (same block, same L2 path):
    // plain stores, no atomics needed. Dedupe by first occurrence of f,
    // ascending-index sum => deterministic.
    int n = sh_n;
    if (tid < 3 * n) {
        int al = tid / n;          // 0..2: local a-row
        int j  = tid - al * n;     // compacted entry
        int fj = cp_f[j];
        bool first = true;
        for (int i = 0; i < j; ++i)
            if (cp_f[i] == fj) { first = false; break; }
        if (first) {
            int a = r0 + al;
            float val = 0.f;
            for (int i = j; i < n; ++i) {
                if (cp_f[i] == fj) {
                    float x = actions[((size_t)b * QQ + cp_q[i]) * AA + a];
                    val += cp_c[i] / (1.f + expf(-x));
                }
            }
            ((float*)dst)[al * ROWF + fj] = val;
        }
    }
}

extern "C" void kernel_launch(void* const* d_in, const int* in_sizes, int n_in,
                              void* d_out, int out_size, void* d_ws, size_t ws_size,
                              hipStream_t stream) {
    const float* pred_logits  = (const float*)d_in[0];
    const float* pred_boxes   = (const float*)d_in[1];
    const float* pred_actions = (const float*)d_in[2];
    const float* pred_hidx    = (const float*)d_in[3];
    const float* pred_oidx    = (const float*)d_in[4];
    const int*   target_sizes = (const int*)d_in[5];

    float* out = (float*)d_out;
    float* out_scores = out;                // B*K
    float* out_labels = out + BB * KK;      // B*K
    float* out_boxes  = out + 2 * BB * KK;  // B*K*4
    float* out_pair   = out + 6 * BB * KK;  // B*117*100*101

    fused_one<<<NBLK, 512, 0, stream>>>(
        pred_logits, pred_boxes, pred_actions, pred_hidx, pred_oidx,
        target_sizes, out_scores, out_labels, out_boxes, out_pair);
}

// Round 11
// 70.243 us; speedup vs baseline: 11.3610x; 1.5610x over previous
//
#include <hip/hip_runtime.h>
#include <cmath>

#define BB 64
#define KK 100
#define QQ 100
#define CC 82
#define AA 118
#define KP1 101
#define AM1 117
#define ROWF (KK * KP1)      // 10100 floats per (b,a) row
#define PB 64                // prep blocks (first in grid)
#define ZB 2496              // zero blocks; each covers 3 rows of one batch
#define ZPB 39               // zero blocks per batch
#define CH4 7575             // float4 per zero block (30300 floats = 3 rows)

typedef float vf4 __attribute__((ext_vector_type(4)));
typedef unsigned long long u64;

struct Lds {
    unsigned char h1[KK], sp[KK];
    int   h[QQ], o[QQ];
    float ms[QQ], c[QQ];
    int   wcnt[2];
    int   cp_f[QQ], cp_q[QQ];
    float cp_c[QQ];
    int   n;
    int   fb;
};

// Full per-batch prep into LDS: masks, argmaxes, ms, winner, compacted list.
// Called by prep blocks (write_small=true) and by fallback path (false).
__device__ __forceinline__ void compute_prep(
    int b, int tid, Lds& s,
    const float* __restrict__ logits, const float* __restrict__ boxes_in,
    const float* __restrict__ actions, const float* __restrict__ hidx,
    const float* __restrict__ oidx, const int* __restrict__ tsizes,
    float* __restrict__ out_scores, float* __restrict__ out_labels,
    float* __restrict__ out_boxes, bool write_small)
{
    if (tid < KK) {
        const float2* l2 = (const float2*)(logits + ((size_t)b * KK + tid) * CC);
        float m = -INFINITY, best = -INFINITY; int bi = 0;
        #pragma unroll
        for (int i = 0; i < CC / 2; ++i) {
            float2 p = l2[i];
            m = fmaxf(m, fmaxf(p.x, p.y));
            if (p.x > best) { best = p.x; bi = 2 * i; }
            if (2 * i + 1 < CC - 1 && p.y > best) { best = p.y; bi = 2 * i + 1; }
        }
        float denom = 0.f;
        #pragma unroll
        for (int i = 0; i < CC / 2; ++i) {
            float2 p = l2[i];
            denom += expf(p.x - m) + expf(p.y - m);
        }
        float score = expf(best - m) / denom;
        s.h1[tid] = (unsigned char)((bi == 1 && score > 0.f) ? 1 : 0);
        s.sp[tid] = (unsigned char)((score > 0.f) ? 1 : 0);
        if (write_small) {
            out_scores[b * KK + tid] = score;
            out_labels[b * KK + tid] = (float)bi;
            const float4 bx = *(const float4*)(boxes_in + ((size_t)b * KK + tid) * 4);
            float ihh = (float)tsizes[b * 2 + 0];
            float iww = (float)tsizes[b * 2 + 1];
            float4 ob;
            ob.x = (bx.x - 0.5f * bx.z) * iww;
            ob.y = (bx.y - 0.5f * bx.w) * ihh;
            ob.z = (bx.x + 0.5f * bx.z) * iww;
            ob.w = (bx.y + 0.5f * bx.w) * ihh;
            *(float4*)(out_boxes + ((size_t)b * KK + tid) * 4) = ob;
        }
    } else if (tid >= 128 && tid < 128 + QQ) {
        int q = tid - 128;   // argmax hidx (first occurrence, strict >) + ms
        const float4* rp = (const float4*)(hidx + ((size_t)b * QQ + q) * KK);
        float best = -INFINITY; int bi = 0;
        #pragma unroll
        for (int i = 0; i < KK / 4; ++i) {
            float4 r = rp[i];
            if (r.x > best) { best = r.x; bi = 4 * i; }
            if (r.y > best) { best = r.y; bi = 4 * i + 1; }
            if (r.z > best) { best = r.z; bi = 4 * i + 2; }
            if (r.w > best) { best = r.w; bi = 4 * i + 3; }
        }
        s.h[q] = bi;
        float x = actions[((size_t)b * QQ + q) * AA + (AA - 1)];
        s.ms[q] = 1.f - 1.f / (1.f + expf(-x));
    } else if (tid >= 256 && tid < 256 + QQ) {
        int q = tid - 256;   // argmax oidx
        const float4* rp = (const float4*)(oidx + ((size_t)b * QQ + q) * KK);
        float best = -INFINITY; int bi = 0;
        #pragma unroll
        for (int i = 0; i < KK / 4; ++i) {
            float4 r = rp[i];
            if (r.x > best) { best = r.x; bi = 4 * i; }
            if (r.y > best) { best = r.y; bi = 4 * i + 1; }
            if (r.z > best) { best = r.z; bi = 4 * i + 2; }
            if (r.w > best) { best = r.w; bi = 4 * i + 3; }
        }
        s.o[q] = bi;
    }
    __syncthreads();

    if (tid < QQ) {
        int hh = s.h[tid], oo = s.o[tid];
        int f = hh * KP1 + oo;
        float myms = s.ms[tid];
        bool winf = true;
        for (int q = 0; q < QQ; ++q) {
            if (s.h[q] * KP1 + s.o[q] == f) {
                float m2 = s.ms[q];
                if (m2 > myms || (m2 == myms && q < tid)) { winf = false; break; }
            }
        }
        float c = myms * (winf ? 2.f : 1.f);
        if (!s.h1[hh] || !s.sp[oo]) c = 0.f;
        s.c[tid] = c;
    }
    __syncthreads();

    if (tid < 128) {
        bool flag = (tid < QQ) && (s.c[tid] != 0.f);
        unsigned long long bal = __ballot(flag);
        if ((tid & 63) == 0) s.wcnt[tid >> 6] = __popcll(bal);
    }
    __syncthreads();

    if (tid < 128) {
        bool flag = (tid < QQ) && (s.c[tid] != 0.f);
        unsigned long long bal = __ballot(flag);
        int base = (tid >> 6) ? s.wcnt[0] : 0;
        if (flag) {
            int pos = base + __popcll(bal & ((1ull << (tid & 63)) - 1ull));
            s.cp_f[pos] = s.h[tid] * KP1 + s.o[tid];
            s.cp_q[pos] = tid;
            s.cp_c[pos] = s.c[tid];
        }
        if (tid == 0) s.n = s.wcnt[0] + s.wcnt[1];
    }
    __syncthreads();
}

// ws2 layout: per batch, word 0 = count (n+1, 0 = not ready), words 1..n =
// entries: bit63 valid | coef_bits<<21 | f<<7 | q. All relaxed atomics;
// readers spin per-word on the valid bit (no producer fence needed).
__global__ __launch_bounds__(512) void mega_kernel(
    const float* __restrict__ logits,   // B,K,C
    const float* __restrict__ boxes_in, // B,K,4
    const float* __restrict__ actions,  // B,Q,A
    const float* __restrict__ hidx,     // B,Q,K
    const float* __restrict__ oidx,     // B,Q,K
    const int*   __restrict__ tsizes,   // B,2
    float* __restrict__ out_scores,     // B,K
    float* __restrict__ out_labels,     // B,K
    float* __restrict__ out_boxes,      // B,K,4
    float* __restrict__ out_pair,       // B,117,100,101
    u64*   __restrict__ ws2)            // B*(QQ+1), memset to 0 per call
{
    int bid = blockIdx.x;
    int tid = threadIdx.x;
    __shared__ Lds s;

    if (bid < PB) {
        int b = bid;
        compute_prep(b, tid, s, logits, boxes_in, actions, hidx, oidx, tsizes,
                     out_scores, out_labels, out_boxes, true);
        u64* wb = ws2 + (size_t)b * (QQ + 1);
        if (tid < s.n) {
            u64 e = (1ULL << 63)
                  | ((u64)__float_as_uint(s.cp_c[tid]) << 21)
                  | ((u64)s.cp_f[tid] << 7)
                  | (u64)s.cp_q[tid];
            atomicExch(&wb[1 + tid], e);
        }
        if (tid == 0) atomicExch(&wb[0], (u64)(s.n + 1));
        return;
    }

    // ---- zero block: 3 rows of batch b ----
    int z = bid - PB;
    int b = z / ZPB;
    int r0 = (z - b * ZPB) * 3;
    vf4* dst = ((vf4*)out_pair) + (size_t)z * CH4;
    const vf4 zero = {0.f, 0.f, 0.f, 0.f};
    #pragma unroll 4
    for (int i = tid; i < CH4; i += 512) dst[i] = zero;

    // ---- fetch this batch's matched list (bounded spin; fallback safe) ----
    if (tid == 0) {
        u64* wb = ws2 + (size_t)b * (QQ + 1);
        int budget = 1 << 18;
        u64 cw;
        do { cw = atomicAdd(&wb[0], 0ULL); } while (cw == 0 && --budget > 0);
        int fb = (cw == 0);
        int n = fb ? 0 : (int)cw - 1;
        for (int j = 0; j < n && !fb; ++j) {
            u64 e;
            do { e = atomicAdd(&wb[1 + j], 0ULL); } while (!(e >> 63) && --budget > 0);
            if (!(e >> 63)) { fb = 1; break; }
            s.cp_c[j] = __uint_as_float((unsigned)(e >> 21));
            s.cp_f[j] = (int)((e >> 7) & 0x3FFF);
            s.cp_q[j] = (int)(e & 0x7F);
        }
        s.n = n;
        s.fb = fb;
    }
    __syncthreads();   // also orders the zero stores before value overwrites

    if (s.fb) {
        // Scheduler never ran prep (dispatch-order paranoia): recompute locally.
        compute_prep(b, tid, s, logits, boxes_in, actions, hidx, oidx, tsizes,
                     out_scores, out_labels, out_boxes, false);
    }

    // ---- overwrite matched cells in this block's 3 rows (plain stores) ----
    int n = s.n;
    if (tid < 3 * n) {
        int al = tid / n;
        int j  = tid - al * n;
        int fj = s.cp_f[j];
        bool first = true;
        for (int i = 0; i < j; ++i)
            if (s.cp_f[i] == fj) { first = false; break; }
        if (first) {
            int a = r0 + al;
            float val = 0.f;
            for (int i = j; i < n; ++i) {
                if (s.cp_f[i] == fj) {
                    float x = actions[((size_t)b * QQ + s.cp_q[i]) * AA + a];
                    val += s.cp_c[i] / (1.f + expf(-x));
                }
            }
            ((float*)dst)[al * ROWF + fj] = val;
        }
    }
}

extern "C" void kernel_launch(void* const* d_in, const int* in_sizes, int n_in,
                              void* d_out, int out_size, void* d_ws, size_t ws_size,
                              hipStream_t stream) {
    const float* pred_logits  = (const float*)d_in[0];
    const float* pred_boxes   = (const float*)d_in[1];
    const float* pred_actions = (const float*)d_in[2];
    const float* pred_hidx    = (const float*)d_in[3];
    const float* pred_oidx    = (const float*)d_in[4];
    const int*   target_sizes = (const int*)d_in[5];

    float* out = (float*)d_out;
    float* out_scores = out;                // B*K
    float* out_labels = out + BB * KK;      // B*K
    float* out_boxes  = out + 2 * BB * KK;  // B*K*4
    float* out_pair   = out + 6 * BB * KK;  // B*117*100*101

    u64* ws2 = (u64*)d_ws;                  // B*(QQ+1) words

    hipMemsetAsync(ws2, 0, (size_t)BB * (QQ + 1) * sizeof(u64), stream);

    mega_kernel<<<PB + ZB, 512, 0, stream>>>(
        pred_logits, pred_boxes, pred_actions, pred_hidx, pred_oidx,
        target_sizes, out_scores, out_labels, out_boxes, out_pair, ws2);
}